// Round 6
// baseline (564.701 us; speedup 1.0000x reference)
//
#include <hip/hip_runtime.h>
#include <math.h>

// Problem dims
#define BT 64       // B*N sequences
#define T 256
#define DM 128      // d_model
#define DI 256      // d_inner
#define DS 16       // d_state
#define DR 8        // dt_rank
#define M_ROWS (BT*T)   // 16384
#define NC 16       // time chunks for parallel scan
#define CL (T/NC)   // chunk length = 16
#define SSZ (BT*DI*DS)  // per-chunk state slab = 262144

__device__ __forceinline__ float fast_silu(float x) {
  return x * __builtin_amdgcn_rcpf(1.0f + __expf(-x));
}
__device__ __forceinline__ float softplus_f(float x) {
  return fmaxf(x, 0.0f) + __logf(1.0f + __expf(-fabsf(x)));
}
// P is stored in the dead u-pre half of xz (cols 0..255 of each 512-wide row)
__device__ __forceinline__ size_t paddr(size_t f) {
  return (f >> 8) * 512 + (f & 255);
}

// ---------------- single-wave 64x64-tile fp32 GEMM, 8x8 microtile ----------------
// Block = 64 threads = 1 wave: NO barriers (same-wave LDS pipe is in-order).
// sA[k][row] transposed, XOR-swizzled: element (k,r) lives at sA[k][r ^ (((k>>2)&3)<<3)].
//   - stores: 2-way bank conflict (free); reads: conflict-free b128 via precomputed bases.
// sB[k][col] linear: float4 stores 2-way (free), b128 reads conflict-free.
// Microtile: rows {4ty+i, 32+4ty+i}, cols {4tx+j, 32+4tx+j}.
// EPI=0: plain store. EPI=1: cols<256 softplus(+dtb)->delta(stride DI); BC tile(bn0=256):
//   col<16 -> Bb, col<32 -> Cb, rest discard (W zero-padded).
template <int EPI>
__global__ __launch_bounds__(64) void gemm_w64(
    const float* __restrict__ A, const float* __restrict__ W,
    float* __restrict__ C, float* __restrict__ Bb, float* __restrict__ Cb,
    const float* __restrict__ dtb, int M, int N, int K) {
  __shared__ float sA[32][64];
  __shared__ float sB[32][64];
  const int bm0 = blockIdx.x * 64, bn0 = blockIdx.y * 64;
  const int tid = threadIdx.x;            // 0..63
  const int tx = tid & 7, ty = tid >> 3;
  const int ar = tid >> 3;                // A staging row (+8i)
  const int ac = (tid & 7) * 4;           // A staging k-col base (4 floats)
  const int sxor = (tid & 3) << 3;        // store-side row XOR (bits 3,4)
  const int bk = tid >> 4;                // B staging k-row (+4i)
  const int bc = (tid & 15) * 4;          // B staging col base

  // read-side XOR'd row bases, selected at compile time per k
  const int ra0 = ty * 4;
  const int rx[4] = {ra0, ra0 ^ 8, ra0 ^ 16, ra0 ^ 24};

  float4 pa[8], pb[8];
  const int NT = K >> 5;

  // prefetch tile 0
#pragma unroll
  for (int i = 0; i < 8; i++)
    pa[i] = *reinterpret_cast<const float4*>(&A[(size_t)(bm0 + 8 * i + ar) * K + ac]);
#pragma unroll
  for (int i = 0; i < 8; i++)
    pb[i] = *reinterpret_cast<const float4*>(&W[(size_t)(4 * i + bk) * N + bn0 + bc]);

  float acc[8][8] = {};

  for (int t = 0; t < NT; t++) {
    // store prefetched tile to LDS (1 wave: program order is the sync)
#pragma unroll
    for (int i = 0; i < 8; i++) {
      const int rs = (8 * i + ar) ^ sxor;
      sA[ac + 0][rs] = pa[i].x;
      sA[ac + 1][rs] = pa[i].y;
      sA[ac + 2][rs] = pa[i].z;
      sA[ac + 3][rs] = pa[i].w;
      *reinterpret_cast<float4*>(&sB[4 * i + bk][bc]) = pb[i];
    }
    if (t + 1 < NT) {       // issue next-tile global loads; hide under compute
      const int k0 = (t + 1) << 5;
#pragma unroll
      for (int i = 0; i < 8; i++)
        pa[i] = *reinterpret_cast<const float4*>(&A[(size_t)(bm0 + 8 * i + ar) * K + k0 + ac]);
#pragma unroll
      for (int i = 0; i < 8; i++)
        pb[i] = *reinterpret_cast<const float4*>(&W[(size_t)(k0 + 4 * i + bk) * N + bn0 + bc]);
    }
#pragma unroll
    for (int k = 0; k < 32; k++) {
      const int r0 = rx[(k >> 2) & 3];    // compile-time per unrolled k
      const float4 a0 = *reinterpret_cast<const float4*>(&sA[k][r0]);
      const float4 a1 = *reinterpret_cast<const float4*>(&sA[k][r0 + 32]);
      const float4 b0 = *reinterpret_cast<const float4*>(&sB[k][tx * 4]);
      const float4 b1 = *reinterpret_cast<const float4*>(&sB[k][tx * 4 + 32]);
      const float av[8] = {a0.x, a0.y, a0.z, a0.w, a1.x, a1.y, a1.z, a1.w};
      const float bv[8] = {b0.x, b0.y, b0.z, b0.w, b1.x, b1.y, b1.z, b1.w};
#pragma unroll
      for (int i = 0; i < 8; i++)
#pragma unroll
        for (int j = 0; j < 8; j++)
          acc[i][j] += av[i] * bv[j];
    }
  }

  if (EPI == 0) {
#pragma unroll
    for (int h = 0; h < 2; h++)
#pragma unroll
      for (int i = 0; i < 4; i++) {
        const size_t m = bm0 + h * 32 + ty * 4 + i;
#pragma unroll
        for (int g = 0; g < 2; g++) {
          float4 v = {acc[h * 4 + i][g * 4 + 0], acc[h * 4 + i][g * 4 + 1],
                      acc[h * 4 + i][g * 4 + 2], acc[h * 4 + i][g * 4 + 3]};
          *reinterpret_cast<float4*>(&C[m * N + bn0 + g * 32 + tx * 4]) = v;
        }
      }
  } else {
    if (bn0 < 256) {
      const float4 bias0 = *reinterpret_cast<const float4*>(&dtb[bn0 + tx * 4]);
      const float4 bias1 = *reinterpret_cast<const float4*>(&dtb[bn0 + 32 + tx * 4]);
#pragma unroll
      for (int h = 0; h < 2; h++)
#pragma unroll
        for (int i = 0; i < 4; i++) {
          const size_t m = bm0 + h * 32 + ty * 4 + i;
          float4 v0, v1;
          v0.x = softplus_f(acc[h * 4 + i][0] + bias0.x);
          v0.y = softplus_f(acc[h * 4 + i][1] + bias0.y);
          v0.z = softplus_f(acc[h * 4 + i][2] + bias0.z);
          v0.w = softplus_f(acc[h * 4 + i][3] + bias0.w);
          v1.x = softplus_f(acc[h * 4 + i][4] + bias1.x);
          v1.y = softplus_f(acc[h * 4 + i][5] + bias1.y);
          v1.z = softplus_f(acc[h * 4 + i][6] + bias1.z);
          v1.w = softplus_f(acc[h * 4 + i][7] + bias1.w);
          *reinterpret_cast<float4*>(&C[m * DI + bn0 + tx * 4]) = v0;
          *reinterpret_cast<float4*>(&C[m * DI + bn0 + 32 + tx * 4]) = v1;
        }
    } else {
      const int col = tx * 4;             // 0..28; group g=1 (32+) discarded
      if (col < 16) {
#pragma unroll
        for (int h = 0; h < 2; h++)
#pragma unroll
          for (int i = 0; i < 4; i++) {
            const size_t m = bm0 + h * 32 + ty * 4 + i;
            float4 v = {acc[h * 4 + i][0], acc[h * 4 + i][1],
                        acc[h * 4 + i][2], acc[h * 4 + i][3]};
            *reinterpret_cast<float4*>(&Bb[m * DS + col]) = v;
          }
      } else {
#pragma unroll
        for (int h = 0; h < 2; h++)
#pragma unroll
          for (int i = 0; i < 4; i++) {
            const size_t m = bm0 + h * 32 + ty * 4 + i;
            float4 v = {acc[h * 4 + i][0], acc[h * 4 + i][1],
                        acc[h * 4 + i][2], acc[h * 4 + i][3]};
            *reinterpret_cast<float4*>(&Cb[m * DS + (col - 16)]) = v;
          }
      }
    }
  }
}

// ---------------- W_big precompute: [l][256 k][320] = [xw_dt @ dtw | xw_BC | 0pad] ----------------
__global__ __launch_bounds__(320) void build_wbig(
    const float* __restrict__ xw, const float* __restrict__ dtw,
    float* __restrict__ Wbig) {
  const int k = blockIdx.x;      // 0..255
  const int l = blockIdx.y;      // 0..1
  const int j = threadIdx.x;     // 0..319
  float v = 0.f;
  if (j < 256) {
#pragma unroll
    for (int r = 0; r < DR; r++)
      v += xw[(size_t)l * DI * 40 + k * 40 + r] * dtw[(size_t)l * DR * DI + r * DI + j];
  } else if (j < 288) {
    v = xw[(size_t)l * DI * 40 + k * 40 + 8 + (j - 256)];
  }
  Wbig[(size_t)l * DI * 320 + k * 320 + j] = v;
}

// ---------------- depthwise causal conv (4-tap) + bias + silu; also silu(res) in place ----------------
__global__ __launch_bounds__(256) void conv_silu_kernel(
    const float* __restrict__ xzr, float* __restrict__ xzw,
    const float* __restrict__ cw, const float* __restrict__ cb,
    float* __restrict__ u) {
  const int m = blockIdx.x;          // (bt*T + t)
  const int d = threadIdx.x;         // 0..255
  const int t = m & (T - 1);
  float acc = cb[d];
#pragma unroll
  for (int j = 0; j < 4; j++) {
    int tt = t - 3 + j;
    if (tt >= 0)
      acc += xzr[(size_t)(m - 3 + j) * 512 + d] * cw[d * 4 + j];
  }
  u[(size_t)m * DI + d] = fast_silu(acc);
  const size_t ra = (size_t)m * 512 + 256 + d;
  xzw[ra] = fast_silu(xzr[ra]);
}

// ---------------- chunked parallel scan (all 16 n-states per thread) ----------------
__global__ __launch_bounds__(256) void scan_phase1(
    const float* __restrict__ delta, const float* __restrict__ u,
    const float* __restrict__ Bb, const float* __restrict__ A_log,
    float* __restrict__ Pal, float* __restrict__ H) {
  const int c  = blockIdx.x;
  const int bt = blockIdx.y;
  const int d  = threadIdx.x;

  float An[16];
  const float4* al = reinterpret_cast<const float4*>(&A_log[d * DS]);
#pragma unroll
  for (int q = 0; q < 4; q++) {
    float4 a = al[q];
    An[q * 4 + 0] = -__expf(a.x);
    An[q * 4 + 1] = -__expf(a.y);
    An[q * 4 + 2] = -__expf(a.z);
    An[q * 4 + 3] = -__expf(a.w);
  }

  float h[16];
#pragma unroll
  for (int n = 0; n < 16; n++) h[n] = 0.f;
  float Sdl = 0.f;

  const size_t m0 = (size_t)bt * T + c * CL;
  for (int t = 0; t < CL; t++) {
    const size_t m = m0 + t;
    const float dl = delta[m * DI + d];
    const float uu = u[m * DI + d];
    const float du = dl * uu;
    Sdl += dl;
    const float4* bp = reinterpret_cast<const float4*>(&Bb[m * DS]);
    const float4 B0 = bp[0], B1 = bp[1], B2 = bp[2], B3 = bp[3];
    const float Bv[16] = {B0.x, B0.y, B0.z, B0.w, B1.x, B1.y, B1.z, B1.w,
                          B2.x, B2.y, B2.z, B2.w, B3.x, B3.y, B3.z, B3.w};
#pragma unroll
    for (int n = 0; n < 16; n++) {
      const float dA = __expf(dl * An[n]);
      h[n] = dA * h[n] + du * Bv[n];
    }
  }

  const size_t idx = ((size_t)c * BT + bt) * 4096 + (size_t)d * 16;
#pragma unroll
  for (int q = 0; q < 4; q++) {
    float4 hv = {h[q * 4 + 0], h[q * 4 + 1], h[q * 4 + 2], h[q * 4 + 3]};
    *reinterpret_cast<float4*>(&H[idx + q * 4]) = hv;
  }
#pragma unroll
  for (int q = 0; q < 4; q++) {
    float4 pv = {__expf(An[q * 4 + 0] * Sdl), __expf(An[q * 4 + 1] * Sdl),
                 __expf(An[q * 4 + 2] * Sdl), __expf(An[q * 4 + 3] * Sdl)};
    *reinterpret_cast<float4*>(&Pal[paddr(idx + q * 4)]) = pv;
  }
}

__global__ __launch_bounds__(256) void scan_phase2(
    const float* __restrict__ Pal, float* __restrict__ H) {
  const size_t i = (size_t)blockIdx.x * 256 + threadIdx.x;   // 0..SSZ-1
  float hin = 0.f;
#pragma unroll
  for (int c = 0; c < NC; c++) {
    const size_t idx = (size_t)c * SSZ + i;
    const float Pv = Pal[paddr(idx)];
    const float Hv = H[idx];
    H[idx] = hin;
    hin = Pv * hin + Hv;
  }
}

__global__ __launch_bounds__(256) void scan_phase3(
    const float* __restrict__ delta, const float* __restrict__ u,
    const float* __restrict__ Bb, const float* __restrict__ Cb,
    const float* __restrict__ xz,            // res half pre-silu'd by conv kernel
    const float* __restrict__ A_log, const float* __restrict__ Dp,
    const float* __restrict__ H, float* __restrict__ g) {
  const int c  = blockIdx.x;
  const int bt = blockIdx.y;
  const int d  = threadIdx.x;

  float An[16];
  const float4* al = reinterpret_cast<const float4*>(&A_log[d * DS]);
#pragma unroll
  for (int q = 0; q < 4; q++) {
    float4 a = al[q];
    An[q * 4 + 0] = -__expf(a.x);
    An[q * 4 + 1] = -__expf(a.y);
    An[q * 4 + 2] = -__expf(a.z);
    An[q * 4 + 3] = -__expf(a.w);
  }
  const float Dpd = Dp[d];

  float h[16];
  const size_t idx = ((size_t)c * BT + bt) * 4096 + (size_t)d * 16;
#pragma unroll
  for (int q = 0; q < 4; q++) {
    float4 hv = *reinterpret_cast<const float4*>(&H[idx + q * 4]);
    h[q * 4 + 0] = hv.x; h[q * 4 + 1] = hv.y; h[q * 4 + 2] = hv.z; h[q * 4 + 3] = hv.w;
  }

  const size_t m0 = (size_t)bt * T + c * CL;
  for (int t = 0; t < CL; t++) {
    const size_t m = m0 + t;
    const float dl = delta[m * DI + d];
    const float uu = u[m * DI + d];
    const float du = dl * uu;
    const float4* bp = reinterpret_cast<const float4*>(&Bb[m * DS]);
    const float4 B0 = bp[0], B1 = bp[1], B2 = bp[2], B3 = bp[3];
    const float4* cp = reinterpret_cast<const float4*>(&Cb[m * DS]);
    const float4 C0 = cp[0], C1 = cp[1], C2 = cp[2], C3 = cp[3];
    const float Bv[16] = {B0.x, B0.y, B0.z, B0.w, B1.x, B1.y, B1.z, B1.w,
                          B2.x, B2.y, B2.z, B2.w, B3.x, B3.y, B3.z, B3.w};
    const float Cv[16] = {C0.x, C0.y, C0.z, C0.w, C1.x, C1.y, C1.z, C1.w,
                          C2.x, C2.y, C2.z, C2.w, C3.x, C3.y, C3.z, C3.w};
    float y = 0.f;
#pragma unroll
    for (int n = 0; n < 16; n++) {
      const float dA = __expf(dl * An[n]);
      h[n] = dA * h[n] + du * Bv[n];
      y += h[n] * Cv[n];
    }
    const float rs = xz[m * 512 + 256 + d];       // already silu'd
    g[m * DI + d] = (y + uu * Dpd) * rs;          // aliases delta (same-thread RAW only)
  }
}

// ---------------- launch ----------------
extern "C" void kernel_launch(void* const* d_in, const int* in_sizes, int n_in,
                              void* d_out, int out_size, void* d_ws, size_t ws_size,
                              hipStream_t stream) {
  const float* x      = (const float*)d_in[0];
  const float* in_w   = (const float*)d_in[1];   // [2,128,512]
  const float* conv_w = (const float*)d_in[2];   // [2,256,1,4]
  const float* conv_b = (const float*)d_in[3];   // [2,256]
  const float* xw     = (const float*)d_in[4];   // [2,256,40]
  const float* dtw    = (const float*)d_in[5];   // [2,8,256]
  const float* dtb    = (const float*)d_in[6];   // [2,256]
  const float* A_log  = (const float*)d_in[7];   // [2,256,16]
  const float* Dp     = (const float*)d_in[8];   // [2,256]
  const float* ow     = (const float*)d_in[9];   // [2,256,128]
  float* out = (float*)d_out;
  float* ws  = (float*)d_ws;

  float* xz = ws;                          // 16384*512; u-pre half hosts P after conv
  float* u  = ws + 8388608;                // 16384*256
  float* dg = ws + 12582912;               // 16384*256 (delta, then g alias)
  float* Bb = ws + 16777216;               // 16384*16
  float* Cb = ws + 17039360;               // 16384*16
  float* hb = ws + 17301504;               // 16384*128
  float* Hb = ws + 19398656;               // NC*SSZ = 4194304 (end 23592960 floats = 94.4MB)
  // W_big scratch lives in d_out (only the final GEMM writes d_out, after last read of W_big)
  float* Wbig = out;                       // 2*256*320 = 163840 <= out_size (2097152)

  build_wbig<<<dim3(DI, 2), 320, 0, stream>>>(xw, dtw, Wbig);

  for (int l = 0; l < 2; l++) {
    const float* Ain = (l == 0) ? x : hb;
    float* dst = (l == 1) ? out : hb;

    gemm_w64<0><<<dim3(M_ROWS / 64, 512 / 64), 64, 0, stream>>>(
        Ain, in_w + (size_t)l * DM * 2 * DI, xz, nullptr, nullptr, nullptr,
        M_ROWS, 2 * DI, DM);

    conv_silu_kernel<<<M_ROWS, 256, 0, stream>>>(
        xz, xz, conv_w + (size_t)l * DI * 4, conv_b + (size_t)l * DI, u);

    gemm_w64<1><<<dim3(M_ROWS / 64, 320 / 64), 64, 0, stream>>>(
        u, Wbig + (size_t)l * DI * 320, dg, Bb, Cb, dtb + (size_t)l * DI,
        M_ROWS, 320, DI);

    scan_phase1<<<dim3(NC, BT), 256, 0, stream>>>(
        dg, u, Bb, A_log + (size_t)l * DI * DS, xz, Hb);

    scan_phase2<<<SSZ / 256, 256, 0, stream>>>(xz, Hb);

    scan_phase3<<<dim3(NC, BT), 256, 0, stream>>>(
        dg, u, Bb, Cb, xz, A_log + (size_t)l * DI * DS, Dp + (size_t)l * DI,
        Hb, dg);

    gemm_w64<0><<<dim3(M_ROWS / 64, DM / 64), 64, 0, stream>>>(
        dg, ow + (size_t)l * DI * DM, dst, nullptr, nullptr, nullptr,
        M_ROWS, DM, DI);
  }
}

// Round 7
// 356.235 us; speedup vs baseline: 1.5852x; 1.5852x over previous
//
#include <hip/hip_runtime.h>
#include <math.h>

// Problem dims
#define BT 64       // B*N sequences
#define T 256
#define DM 128      // d_model
#define DI 256      // d_inner
#define DS 16       // d_state
#define DR 8        // dt_rank
#define M_ROWS (BT*T)   // 16384
#define NC 16       // time chunks for parallel scan
#define CL (T/NC)   // chunk length = 16
#define SSZ (BT*DI*DS)  // per-chunk state slab = 262144

__device__ __forceinline__ float fast_silu(float x) {
  return x * __builtin_amdgcn_rcpf(1.0f + __expf(-x));
}
__device__ __forceinline__ float softplus_f(float x) {
  return fmaxf(x, 0.0f) + __logf(1.0f + __expf(-fabsf(x)));
}
// P is stored in the dead u-pre half of xz (cols 0..255 of each 512-wide row)
__device__ __forceinline__ size_t paddr(size_t f) {
  return (f >> 8) * 512 + (f & 255);
}

// ---------------- 128x64-tile fp32 GEMM, 256 threads, 8x4 microtile ----------------
// sA: flat [32][128], element (k,r) stored at k*128 + (r ^ (((k>>2)&3)<<3)).
//   store banks 2-way (free); reads are 16B-aligned b128, logical rows fixed,
//   16 banks x 16-lane broadcast (free).
// sB[32][64] linear: f4 stores 2-way; b128 reads 2-way (free).
// Per k per thread: 32 FMA + 3 b128 LDS reads -> ~94% FMA issue density.
// EPI=0: plain store. EPI=1 (W_big): cols<256 softplus(+dtb)->delta(stride DI);
//   BC tile (bn0=256): col<16 -> Bb, col<32 -> Cb, rest discard (W zero-padded).
template <int EPI>
__global__ __launch_bounds__(256) void gemm_t(
    const float* __restrict__ A, const float* __restrict__ W,
    float* __restrict__ C, float* __restrict__ Bb, float* __restrict__ Cb,
    const float* __restrict__ dtb, int M, int N, int K) {
  __shared__ float sA[32 * 128];
  __shared__ float sB[32][64];
  const int bm0 = blockIdx.x * 128, bn0 = blockIdx.y * 64;
  const int tid = threadIdx.x;
  const int tx = tid & 15;          // 16 col-groups of 4
  const int ty = tid >> 4;          // 16 row-groups of 8
  const int ar = tid >> 3;          // A staging row (+32i)
  const int ac = (tid & 7) * 4;     // A staging k base (4 k's)
  const int sxor = (tid & 3) << 3;  // store-side row XOR (bits 3..4)
  const int bk = tid >> 4;          // B staging k row (+16i)
  const int bc = (tid & 15) * 4;    // B staging col base
  // read-side swizzled row bases per s=(k>>2)&3 (logical rows ty*8..ty*8+7)
  const int rb[4] = {(ty ^ 0) * 8, (ty ^ 1) * 8, (ty ^ 2) * 8, (ty ^ 3) * 8};

  const float* pa = A + (size_t)(bm0 + ar) * K + ac;
  const float* pw = W + (size_t)bk * N + bn0 + bc;
  const size_t astep = (size_t)32 * K;   // +32 rows
  const size_t wstep = (size_t)16 * N;   // +16 k-rows

  float4 pra[4], prb[2];
#pragma unroll
  for (int i = 0; i < 4; i++)
    pra[i] = *reinterpret_cast<const float4*>(pa + i * astep);
#pragma unroll
  for (int i = 0; i < 2; i++)
    prb[i] = *reinterpret_cast<const float4*>(pw + i * wstep);

  float acc[8][4] = {};
  const int NT = K >> 5;

  for (int t = 0; t < NT; t++) {
    if (t > 0) __syncthreads();
#pragma unroll
    for (int i = 0; i < 4; i++) {
      const int r = (ar + 32 * i) ^ sxor;
      sA[(ac + 0) * 128 + r] = pra[i].x;
      sA[(ac + 1) * 128 + r] = pra[i].y;
      sA[(ac + 2) * 128 + r] = pra[i].z;
      sA[(ac + 3) * 128 + r] = pra[i].w;
    }
#pragma unroll
    for (int i = 0; i < 2; i++)
      *reinterpret_cast<float4*>(&sB[bk + 16 * i][bc]) = prb[i];
    __syncthreads();

    if (t + 1 < NT) {                 // issue next-tile loads under compute
      pa += 32;
      pw += (size_t)32 * N;
#pragma unroll
      for (int i = 0; i < 4; i++)
        pra[i] = *reinterpret_cast<const float4*>(pa + i * astep);
#pragma unroll
      for (int i = 0; i < 2; i++)
        prb[i] = *reinterpret_cast<const float4*>(pw + i * wstep);
    }

#pragma unroll
    for (int k = 0; k < 32; k++) {
      const int r0 = k * 128 + rb[(k >> 2) & 3];   // compile-time s per unrolled k
      const float4 a0 = *reinterpret_cast<const float4*>(&sA[r0]);
      const float4 a1 = *reinterpret_cast<const float4*>(&sA[r0 + 4]);
      const float4 bv = *reinterpret_cast<const float4*>(&sB[k][tx * 4]);
      const float av[8] = {a0.x, a0.y, a0.z, a0.w, a1.x, a1.y, a1.z, a1.w};
      const float bvv[4] = {bv.x, bv.y, bv.z, bv.w};
#pragma unroll
      for (int i = 0; i < 8; i++)
#pragma unroll
        for (int j = 0; j < 4; j++)
          acc[i][j] += av[i] * bvv[j];
    }
  }

  if (EPI == 0) {
#pragma unroll
    for (int i = 0; i < 8; i++) {
      const size_t m = bm0 + ty * 8 + i;
      float4 v = {acc[i][0], acc[i][1], acc[i][2], acc[i][3]};
      *reinterpret_cast<float4*>(&C[m * N + bn0 + tx * 4]) = v;
    }
  } else {
    if (bn0 < 256) {
      const int col = bn0 + tx * 4;
      const float4 bias = *reinterpret_cast<const float4*>(&dtb[col]);
#pragma unroll
      for (int i = 0; i < 8; i++) {
        const size_t m = bm0 + ty * 8 + i;
        float4 v;
        v.x = softplus_f(acc[i][0] + bias.x);
        v.y = softplus_f(acc[i][1] + bias.y);
        v.z = softplus_f(acc[i][2] + bias.z);
        v.w = softplus_f(acc[i][3] + bias.w);
        *reinterpret_cast<float4*>(&C[m * DI + col]) = v;
      }
    } else {
      const int col = tx * 4;        // 0..60 within BC tile
      if (col < 16) {
#pragma unroll
        for (int i = 0; i < 8; i++) {
          const size_t m = bm0 + ty * 8 + i;
          float4 v = {acc[i][0], acc[i][1], acc[i][2], acc[i][3]};
          *reinterpret_cast<float4*>(&Bb[m * DS + col]) = v;
        }
      } else if (col < 32) {
#pragma unroll
        for (int i = 0; i < 8; i++) {
          const size_t m = bm0 + ty * 8 + i;
          float4 v = {acc[i][0], acc[i][1], acc[i][2], acc[i][3]};
          *reinterpret_cast<float4*>(&Cb[m * DS + (col - 16)]) = v;
        }
      }
    }
  }
}

// ---------------- W_big precompute: [l][256 k][320] = [xw_dt @ dtw | xw_BC | 0pad] ----------------
__global__ __launch_bounds__(320) void build_wbig(
    const float* __restrict__ xw, const float* __restrict__ dtw,
    float* __restrict__ Wbig) {
  const int k = blockIdx.x;      // 0..255
  const int l = blockIdx.y;      // 0..1
  const int j = threadIdx.x;     // 0..319
  float v = 0.f;
  if (j < 256) {
#pragma unroll
    for (int r = 0; r < DR; r++)
      v += xw[(size_t)l * DI * 40 + k * 40 + r] * dtw[(size_t)l * DR * DI + r * DI + j];
  } else if (j < 288) {
    v = xw[(size_t)l * DI * 40 + k * 40 + 8 + (j - 256)];
  }
  Wbig[(size_t)l * DI * 320 + k * 320 + j] = v;
}

// ---------------- depthwise causal conv (4-tap) + bias + silu; also silu(res) in place ----------------
__global__ __launch_bounds__(256) void conv_silu_kernel(
    const float* __restrict__ xzr, float* __restrict__ xzw,
    const float* __restrict__ cw, const float* __restrict__ cb,
    float* __restrict__ u) {
  const int m = blockIdx.x;          // (bt*T + t)
  const int d = threadIdx.x;         // 0..255
  const int t = m & (T - 1);
  float acc = cb[d];
#pragma unroll
  for (int j = 0; j < 4; j++) {
    int tt = t - 3 + j;
    if (tt >= 0)
      acc += xzr[(size_t)(m - 3 + j) * 512 + d] * cw[d * 4 + j];
  }
  u[(size_t)m * DI + d] = fast_silu(acc);
  const size_t ra = (size_t)m * 512 + 256 + d;
  xzw[ra] = fast_silu(xzr[ra]);
}

// ---------------- chunked parallel scan (all 16 n-states per thread) ----------------
__global__ __launch_bounds__(256) void scan_phase1(
    const float* __restrict__ delta, const float* __restrict__ u,
    const float* __restrict__ Bb, const float* __restrict__ A_log,
    float* __restrict__ Pal, float* __restrict__ H) {
  const int c  = blockIdx.x;
  const int bt = blockIdx.y;
  const int d  = threadIdx.x;

  float An[16];
  const float4* al = reinterpret_cast<const float4*>(&A_log[d * DS]);
#pragma unroll
  for (int q = 0; q < 4; q++) {
    float4 a = al[q];
    An[q * 4 + 0] = -__expf(a.x);
    An[q * 4 + 1] = -__expf(a.y);
    An[q * 4 + 2] = -__expf(a.z);
    An[q * 4 + 3] = -__expf(a.w);
  }

  float h[16];
#pragma unroll
  for (int n = 0; n < 16; n++) h[n] = 0.f;
  float Sdl = 0.f;

  const size_t m0 = (size_t)bt * T + c * CL;
  for (int t = 0; t < CL; t++) {
    const size_t m = m0 + t;
    const float dl = delta[m * DI + d];
    const float uu = u[m * DI + d];
    const float du = dl * uu;
    Sdl += dl;
    const float4* bp = reinterpret_cast<const float4*>(&Bb[m * DS]);
    const float4 B0 = bp[0], B1 = bp[1], B2 = bp[2], B3 = bp[3];
    const float Bv[16] = {B0.x, B0.y, B0.z, B0.w, B1.x, B1.y, B1.z, B1.w,
                          B2.x, B2.y, B2.z, B2.w, B3.x, B3.y, B3.z, B3.w};
#pragma unroll
    for (int n = 0; n < 16; n++) {
      const float dA = __expf(dl * An[n]);
      h[n] = dA * h[n] + du * Bv[n];
    }
  }

  const size_t idx = ((size_t)c * BT + bt) * 4096 + (size_t)d * 16;
#pragma unroll
  for (int q = 0; q < 4; q++) {
    float4 hv = {h[q * 4 + 0], h[q * 4 + 1], h[q * 4 + 2], h[q * 4 + 3]};
    *reinterpret_cast<float4*>(&H[idx + q * 4]) = hv;
  }
#pragma unroll
  for (int q = 0; q < 4; q++) {
    float4 pv = {__expf(An[q * 4 + 0] * Sdl), __expf(An[q * 4 + 1] * Sdl),
                 __expf(An[q * 4 + 2] * Sdl), __expf(An[q * 4 + 3] * Sdl)};
    *reinterpret_cast<float4*>(&Pal[paddr(idx + q * 4)]) = pv;
  }
}

__global__ __launch_bounds__(256) void scan_phase2(
    const float* __restrict__ Pal, float* __restrict__ H) {
  const size_t i = (size_t)blockIdx.x * 256 + threadIdx.x;   // 0..SSZ-1
  float hin = 0.f;
#pragma unroll
  for (int c = 0; c < NC; c++) {
    const size_t idx = (size_t)c * SSZ + i;
    const float Pv = Pal[paddr(idx)];
    const float Hv = H[idx];
    H[idx] = hin;
    hin = Pv * hin + Hv;
  }
}

__global__ __launch_bounds__(256) void scan_phase3(
    const float* __restrict__ delta, const float* __restrict__ u,
    const float* __restrict__ Bb, const float* __restrict__ Cb,
    const float* __restrict__ xz,            // res half pre-silu'd by conv kernel
    const float* __restrict__ A_log, const float* __restrict__ Dp,
    const float* __restrict__ H, float* __restrict__ g) {
  const int c  = blockIdx.x;
  const int bt = blockIdx.y;
  const int d  = threadIdx.x;

  float An[16];
  const float4* al = reinterpret_cast<const float4*>(&A_log[d * DS]);
#pragma unroll
  for (int q = 0; q < 4; q++) {
    float4 a = al[q];
    An[q * 4 + 0] = -__expf(a.x);
    An[q * 4 + 1] = -__expf(a.y);
    An[q * 4 + 2] = -__expf(a.z);
    An[q * 4 + 3] = -__expf(a.w);
  }
  const float Dpd = Dp[d];

  float h[16];
  const size_t idx = ((size_t)c * BT + bt) * 4096 + (size_t)d * 16;
#pragma unroll
  for (int q = 0; q < 4; q++) {
    float4 hv = *reinterpret_cast<const float4*>(&H[idx + q * 4]);
    h[q * 4 + 0] = hv.x; h[q * 4 + 1] = hv.y; h[q * 4 + 2] = hv.z; h[q * 4 + 3] = hv.w;
  }

  const size_t m0 = (size_t)bt * T + c * CL;
  for (int t = 0; t < CL; t++) {
    const size_t m = m0 + t;
    const float dl = delta[m * DI + d];
    const float uu = u[m * DI + d];
    const float du = dl * uu;
    const float4* bp = reinterpret_cast<const float4*>(&Bb[m * DS]);
    const float4 B0 = bp[0], B1 = bp[1], B2 = bp[2], B3 = bp[3];
    const float4* cp = reinterpret_cast<const float4*>(&Cb[m * DS]);
    const float4 C0 = cp[0], C1 = cp[1], C2 = cp[2], C3 = cp[3];
    const float Bv[16] = {B0.x, B0.y, B0.z, B0.w, B1.x, B1.y, B1.z, B1.w,
                          B2.x, B2.y, B2.z, B2.w, B3.x, B3.y, B3.z, B3.w};
    const float Cv[16] = {C0.x, C0.y, C0.z, C0.w, C1.x, C1.y, C1.z, C1.w,
                          C2.x, C2.y, C2.z, C2.w, C3.x, C3.y, C3.z, C3.w};
    float y = 0.f;
#pragma unroll
    for (int n = 0; n < 16; n++) {
      const float dA = __expf(dl * An[n]);
      h[n] = dA * h[n] + du * Bv[n];
      y += h[n] * Cv[n];
    }
    const float rs = xz[m * 512 + 256 + d];       // already silu'd
    g[m * DI + d] = (y + uu * Dpd) * rs;          // aliases delta (same-thread RAW only)
  }
}

// ---------------- launch ----------------
extern "C" void kernel_launch(void* const* d_in, const int* in_sizes, int n_in,
                              void* d_out, int out_size, void* d_ws, size_t ws_size,
                              hipStream_t stream) {
  const float* x      = (const float*)d_in[0];
  const float* in_w   = (const float*)d_in[1];   // [2,128,512]
  const float* conv_w = (const float*)d_in[2];   // [2,256,1,4]
  const float* conv_b = (const float*)d_in[3];   // [2,256]
  const float* xw     = (const float*)d_in[4];   // [2,256,40]
  const float* dtw    = (const float*)d_in[5];   // [2,8,256]
  const float* dtb    = (const float*)d_in[6];   // [2,256]
  const float* A_log  = (const float*)d_in[7];   // [2,256,16]
  const float* Dp     = (const float*)d_in[8];   // [2,256]
  const float* ow     = (const float*)d_in[9];   // [2,256,128]
  float* out = (float*)d_out;
  float* ws  = (float*)d_ws;

  float* xz = ws;                          // 16384*512; u-pre half hosts P after conv
  float* u  = ws + 8388608;                // 16384*256
  float* dg = ws + 12582912;               // 16384*256 (delta, then g alias)
  float* Bb = ws + 16777216;               // 16384*16
  float* Cb = ws + 17039360;               // 16384*16
  float* hb = ws + 17301504;               // 16384*128
  float* Hb = ws + 19398656;               // NC*SSZ = 4194304 (end 23592960 floats = 94.4MB)
  // W_big scratch lives in d_out (only the final GEMM writes d_out, after last read of W_big)
  float* Wbig = out;                       // 2*256*320 = 163840 <= out_size (2097152)

  build_wbig<<<dim3(DI, 2), 320, 0, stream>>>(xw, dtw, Wbig);

  for (int l = 0; l < 2; l++) {
    const float* Ain = (l == 0) ? x : hb;
    float* dst = (l == 1) ? out : hb;

    gemm_t<0><<<dim3(M_ROWS / 128, 512 / 64), 256, 0, stream>>>(
        Ain, in_w + (size_t)l * DM * 2 * DI, xz, nullptr, nullptr, nullptr,
        M_ROWS, 2 * DI, DM);

    conv_silu_kernel<<<M_ROWS, 256, 0, stream>>>(
        xz, xz, conv_w + (size_t)l * DI * 4, conv_b + (size_t)l * DI, u);

    gemm_t<1><<<dim3(M_ROWS / 128, 320 / 64), 256, 0, stream>>>(
        u, Wbig + (size_t)l * DI * 320, dg, Bb, Cb, dtb + (size_t)l * DI,
        M_ROWS, 320, DI);

    scan_phase1<<<dim3(NC, BT), 256, 0, stream>>>(
        dg, u, Bb, A_log + (size_t)l * DI * DS, xz, Hb);

    scan_phase2<<<SSZ / 256, 256, 0, stream>>>(xz, Hb);

    scan_phase3<<<dim3(NC, BT), 256, 0, stream>>>(
        dg, u, Bb, Cb, xz, A_log + (size_t)l * DI * DS, Dp + (size_t)l * DI,
        Hb, dg);

    gemm_t<0><<<dim3(M_ROWS / 128, DM / 64), 256, 0, stream>>>(
        dg, ow + (size_t)l * DI * DM, dst, nullptr, nullptr, nullptr,
        M_ROWS, DM, DI);
  }
}

// Round 8
// 301.405 us; speedup vs baseline: 1.8736x; 1.1819x over previous
//
#include <hip/hip_runtime.h>
#include <math.h>

// Problem dims
#define BT 64       // B*N sequences
#define T 256
#define DM 128      // d_model
#define DI 256      // d_inner
#define DS 16       // d_state
#define DR 8        // dt_rank
#define M_ROWS (BT*T)   // 16384
#define NC 8        // time chunks for parallel scan
#define CL (T/NC)   // chunk length = 32
#define SSZ (BT*DI*DS)  // per-chunk state slab = 262144

typedef __attribute__((ext_vector_type(8))) short short8v;   // 8 bf16
typedef __attribute__((ext_vector_type(4))) float f32x4;     // MFMA acc
typedef __attribute__((ext_vector_type(4))) unsigned int uint4v;
union U8 { unsigned int u[4]; uint4v v; short8v s; };

__device__ __forceinline__ float fast_silu(float x) {
  return x * __builtin_amdgcn_rcpf(1.0f + __expf(-x));
}
__device__ __forceinline__ float softplus_f(float x) {
  return fmaxf(x, 0.0f) + __logf(1.0f + __expf(-fabsf(x)));
}
// P is stored in the dead u-pre half of xz (cols 0..255 of each 512-wide row)
__device__ __forceinline__ size_t paddr(size_t f) {
  return (f >> 8) * 512 + (f & 255);
}

// exact 3-way bf16 split of 8 fp32 (truncation; subtractions exact)
__device__ __forceinline__ void split3(const float* x, short8v& o1, short8v& o2, short8v& o3) {
  unsigned int h1[8], h2[8], h3[8];
#pragma unroll
  for (int e = 0; e < 8; e++) {
    const float xe = x[e];
    const unsigned int a = __float_as_uint(xe) & 0xFFFF0000u;
    const float r1 = xe - __uint_as_float(a);
    const unsigned int b = __float_as_uint(r1) & 0xFFFF0000u;
    const float r2 = r1 - __uint_as_float(b);
    const unsigned int c = __float_as_uint(r2) & 0xFFFF0000u;
    h1[e] = a; h2[e] = b; h3[e] = c;
  }
  U8 u1, u2, u3;
#pragma unroll
  for (int q = 0; q < 4; q++) {
    u1.u[q] = (h1[2 * q] >> 16) | (h1[2 * q + 1] & 0xFFFF0000u);
    u2.u[q] = (h2[2 * q] >> 16) | (h2[2 * q + 1] & 0xFFFF0000u);
    u3.u[q] = (h3[2 * q] >> 16) | (h3[2 * q + 1] & 0xFFFF0000u);
  }
  o1 = u1.s; o2 = u2.s; o3 = u3.s;
}

// ---------------- W pre-split into fragment-direct plane layout ----------------
// chunk (p, ks, cf): 64 lanes x 16B; lane l elem e = W[ks*32+(l>>4)*8+e][cf*16+(l&15)]
// dst u32 idx = (((p*Kt+ks)*NF+cf)*64 + l)*4 ; per-layer stride = 3*Kt*NF*256 u32
__global__ __launch_bounds__(64) void prep_planes(
    const float* __restrict__ W, unsigned int* __restrict__ dst, int K, int Nn) {
  const int NF = Nn / 16, Kt = K >> 5;
  const int layer = blockIdx.y;
  W += (size_t)layer * K * Nn;
  dst += (size_t)layer * 3 * Kt * NF * 256;
  const int ks = blockIdx.x / NF, cf = blockIdx.x % NF;
  const int l = threadIdx.x;
  const int col = cf * 16 + (l & 15);
  const int k0 = ks * 32 + (l >> 4) * 8;
  float x[8];
#pragma unroll
  for (int e = 0; e < 8; e++) x[e] = W[(size_t)(k0 + e) * Nn + col];
  short8v p1, p2, p3;
  split3(x, p1, p2, p3);
  U8 t;
  const size_t pstride = (size_t)Kt * NF * 256;
  const size_t base = (((size_t)ks * NF + cf) * 64 + l) * 4;
  t.s = p1; *reinterpret_cast<uint4v*>(dst + base) = t.v;
  t.s = p2; *reinterpret_cast<uint4v*>(dst + pstride + base) = t.v;
  t.s = p3; *reinterpret_cast<uint4v*>(dst + 2 * pstride + base) = t.v;
}

// ---------------- MFMA split-bf16 GEMM: wave-per-64x(16*CF) tile, no LDS ----------------
// 6-term split accumulation into fp32 AGPRs. B from pre-split planes (frag-direct),
// A fp32 from global, split in-reg. C map (m89): row=(l>>4)*4+reg, col=l&15.
// EPI=0: plain store (stride Nn). EPI=1: col<256 softplus(+dtb)->C stride DI;
//   col 256-271 -> Bb; 272-287 -> Cb; >=288 discard.
template <int CF, int EPI>
__global__ __launch_bounds__(256, 2) void gemm_mfma(
    const float* __restrict__ A, const unsigned int* __restrict__ Bp,
    float* __restrict__ C, float* __restrict__ Bb, float* __restrict__ Cb,
    const float* __restrict__ dtb, int M, int Nn, int K) {
  const int NWC = Nn / (16 * CF);
  const int wid = blockIdx.x * 4 + (threadIdx.x >> 6);
  const int l = threadIdx.x & 63;
  const int mw = wid / NWC, nw = wid % NWC;
  const int wr0 = mw * 64, wc0 = nw * 16 * CF;
  const int rA = l & 15, kg = l >> 4;
  const int NF = Nn / 16, Kt = K >> 5;

  f32x4 acc[4][CF];
#pragma unroll
  for (int fr = 0; fr < 4; fr++)
#pragma unroll
    for (int j = 0; j < CF; j++) acc[fr][j] = (f32x4){0.f, 0.f, 0.f, 0.f};

  for (int ks = 0; ks < Kt; ks++) {
    // B fragments: 3 planes x CF, single b128 loads (L2-hot)
    short8v bf[3][CF];
#pragma unroll
    for (int p = 0; p < 3; p++)
#pragma unroll
      for (int j = 0; j < CF; j++) {
        U8 t;
        t.v = *reinterpret_cast<const uint4v*>(
            Bp + ((((size_t)p * Kt + ks) * NF + (wc0 >> 4) + j) * 64 + l) * 4);
        bf[p][j] = t.s;
      }
    // A fragments: load fp32, split to 3 planes in-reg (VALU overlaps MFMA pipe)
    short8v a1[4], a2[4], a3[4];
#pragma unroll
    for (int fr = 0; fr < 4; fr++) {
      const float* ap = A + (size_t)(wr0 + fr * 16 + rA) * K + ks * 32 + kg * 8;
      float x[8];
      *reinterpret_cast<float4*>(x) = *reinterpret_cast<const float4*>(ap);
      *reinterpret_cast<float4*>(x + 4) = *reinterpret_cast<const float4*>(ap + 4);
      split3(x, a1[fr], a2[fr], a3[fr]);
    }
    // 6-term accumulation (h1h1, h1h2, h2h1, h1h3, h3h1, h2h2)
#pragma unroll
    for (int fr = 0; fr < 4; fr++)
#pragma unroll
      for (int j = 0; j < CF; j++) {
        f32x4 c = acc[fr][j];
        c = __builtin_amdgcn_mfma_f32_16x16x32_bf16(a1[fr], bf[0][j], c, 0, 0, 0);
        c = __builtin_amdgcn_mfma_f32_16x16x32_bf16(a1[fr], bf[1][j], c, 0, 0, 0);
        c = __builtin_amdgcn_mfma_f32_16x16x32_bf16(a2[fr], bf[0][j], c, 0, 0, 0);
        c = __builtin_amdgcn_mfma_f32_16x16x32_bf16(a1[fr], bf[2][j], c, 0, 0, 0);
        c = __builtin_amdgcn_mfma_f32_16x16x32_bf16(a3[fr], bf[0][j], c, 0, 0, 0);
        c = __builtin_amdgcn_mfma_f32_16x16x32_bf16(a2[fr], bf[1][j], c, 0, 0, 0);
        acc[fr][j] = c;
      }
  }

  const int cr = (l >> 4) * 4;   // C row base within frag
  const int cc = l & 15;         // C col within frag
  if (EPI == 0) {
#pragma unroll
    for (int fr = 0; fr < 4; fr++)
#pragma unroll
      for (int j = 0; j < CF; j++) {
        const int col = wc0 + j * 16 + cc;
#pragma unroll
        for (int r = 0; r < 4; r++)
          C[(size_t)(wr0 + fr * 16 + cr + r) * Nn + col] = acc[fr][j][r];
      }
  } else {
#pragma unroll
    for (int fr = 0; fr < 4; fr++)
#pragma unroll
      for (int j = 0; j < CF; j++) {
        const int col = wc0 + j * 16 + cc;
        if (col < 256) {
          const float bias = dtb[col];
#pragma unroll
          for (int r = 0; r < 4; r++)
            C[(size_t)(wr0 + fr * 16 + cr + r) * DI + col] =
                softplus_f(acc[fr][j][r] + bias);
        } else if (col < 272) {
#pragma unroll
          for (int r = 0; r < 4; r++)
            Bb[(size_t)(wr0 + fr * 16 + cr + r) * DS + (col - 256)] = acc[fr][j][r];
        } else if (col < 288) {
#pragma unroll
          for (int r = 0; r < 4; r++)
            Cb[(size_t)(wr0 + fr * 16 + cr + r) * DS + (col - 272)] = acc[fr][j][r];
        }
      }
  }
}

// ---------------- W_big precompute: [l][256 k][320] = [xw_dt @ dtw | xw_BC | 0pad] ----------------
__global__ __launch_bounds__(320) void build_wbig(
    const float* __restrict__ xw, const float* __restrict__ dtw,
    float* __restrict__ Wbig) {
  const int k = blockIdx.x;      // 0..255
  const int l = blockIdx.y;      // 0..1
  const int j = threadIdx.x;     // 0..319
  float v = 0.f;
  if (j < 256) {
#pragma unroll
    for (int r = 0; r < DR; r++)
      v += xw[(size_t)l * DI * 40 + k * 40 + r] * dtw[(size_t)l * DR * DI + r * DI + j];
  } else if (j < 288) {
    v = xw[(size_t)l * DI * 40 + k * 40 + 8 + (j - 256)];
  }
  Wbig[(size_t)l * DI * 320 + k * 320 + j] = v;
}

// ---------------- depthwise causal conv (4-tap) + bias + silu; also silu(res) in place ----------------
__global__ __launch_bounds__(256) void conv_silu_kernel(
    const float* __restrict__ xzr, float* __restrict__ xzw,
    const float* __restrict__ cw, const float* __restrict__ cb,
    float* __restrict__ u) {
  const int m = blockIdx.x;          // (bt*T + t)
  const int d = threadIdx.x;         // 0..255
  const int t = m & (T - 1);
  float acc = cb[d];
#pragma unroll
  for (int j = 0; j < 4; j++) {
    int tt = t - 3 + j;
    if (tt >= 0)
      acc += xzr[(size_t)(m - 3 + j) * 512 + d] * cw[d * 4 + j];
  }
  u[(size_t)m * DI + d] = fast_silu(acc);
  const size_t ra = (size_t)m * 512 + 256 + d;
  xzw[ra] = fast_silu(xzr[ra]);
}

// ---------------- chunked parallel scan (all 16 n-states per thread) ----------------
__global__ __launch_bounds__(256) void scan_phase1(
    const float* __restrict__ delta, const float* __restrict__ u,
    const float* __restrict__ Bb, const float* __restrict__ A_log,
    float* __restrict__ Pal, float* __restrict__ H) {
  const int c  = blockIdx.x;
  const int bt = blockIdx.y;
  const int d  = threadIdx.x;

  float An[16];
  const float4* al = reinterpret_cast<const float4*>(&A_log[d * DS]);
#pragma unroll
  for (int q = 0; q < 4; q++) {
    float4 a = al[q];
    An[q * 4 + 0] = -__expf(a.x);
    An[q * 4 + 1] = -__expf(a.y);
    An[q * 4 + 2] = -__expf(a.z);
    An[q * 4 + 3] = -__expf(a.w);
  }

  float h[16];
#pragma unroll
  for (int n = 0; n < 16; n++) h[n] = 0.f;
  float Sdl = 0.f;

  const size_t m0 = (size_t)bt * T + c * CL;
  for (int t = 0; t < CL; t++) {
    const size_t m = m0 + t;
    const float dl = delta[m * DI + d];
    const float uu = u[m * DI + d];
    const float du = dl * uu;
    Sdl += dl;
    const float4* bp = reinterpret_cast<const float4*>(&Bb[m * DS]);
    const float4 B0 = bp[0], B1 = bp[1], B2 = bp[2], B3 = bp[3];
    const float Bv[16] = {B0.x, B0.y, B0.z, B0.w, B1.x, B1.y, B1.z, B1.w,
                          B2.x, B2.y, B2.z, B2.w, B3.x, B3.y, B3.z, B3.w};
#pragma unroll
    for (int n = 0; n < 16; n++) {
      const float dA = __expf(dl * An[n]);
      h[n] = dA * h[n] + du * Bv[n];
    }
  }

  const size_t idx = ((size_t)c * BT + bt) * 4096 + (size_t)d * 16;
#pragma unroll
  for (int q = 0; q < 4; q++) {
    float4 hv = {h[q * 4 + 0], h[q * 4 + 1], h[q * 4 + 2], h[q * 4 + 3]};
    *reinterpret_cast<float4*>(&H[idx + q * 4]) = hv;
  }
#pragma unroll
  for (int q = 0; q < 4; q++) {
    float4 pv = {__expf(An[q * 4 + 0] * Sdl), __expf(An[q * 4 + 1] * Sdl),
                 __expf(An[q * 4 + 2] * Sdl), __expf(An[q * 4 + 3] * Sdl)};
    *reinterpret_cast<float4*>(&Pal[paddr(idx + q * 4)]) = pv;
  }
}

__global__ __launch_bounds__(256) void scan_phase2(
    const float* __restrict__ Pal, float* __restrict__ H) {
  const size_t i = (size_t)blockIdx.x * 256 + threadIdx.x;   // 0..SSZ-1
  float hin = 0.f;
#pragma unroll
  for (int c = 0; c < NC; c++) {
    const size_t idx = (size_t)c * SSZ + i;
    const float Pv = Pal[paddr(idx)];
    const float Hv = H[idx];
    H[idx] = hin;
    hin = Pv * hin + Hv;
  }
}

__global__ __launch_bounds__(256) void scan_phase3(
    const float* __restrict__ delta, const float* __restrict__ u,
    const float* __restrict__ Bb, const float* __restrict__ Cb,
    const float* __restrict__ xz,            // res half pre-silu'd by conv kernel
    const float* __restrict__ A_log, const float* __restrict__ Dp,
    const float* __restrict__ H, float* __restrict__ g) {
  const int c  = blockIdx.x;
  const int bt = blockIdx.y;
  const int d  = threadIdx.x;

  float An[16];
  const float4* al = reinterpret_cast<const float4*>(&A_log[d * DS]);
#pragma unroll
  for (int q = 0; q < 4; q++) {
    float4 a = al[q];
    An[q * 4 + 0] = -__expf(a.x);
    An[q * 4 + 1] = -__expf(a.y);
    An[q * 4 + 2] = -__expf(a.z);
    An[q * 4 + 3] = -__expf(a.w);
  }
  const float Dpd = Dp[d];

  float h[16];
  const size_t idx = ((size_t)c * BT + bt) * 4096 + (size_t)d * 16;
#pragma unroll
  for (int q = 0; q < 4; q++) {
    float4 hv = *reinterpret_cast<const float4*>(&H[idx + q * 4]);
    h[q * 4 + 0] = hv.x; h[q * 4 + 1] = hv.y; h[q * 4 + 2] = hv.z; h[q * 4 + 3] = hv.w;
  }

  const size_t m0 = (size_t)bt * T + c * CL;
  for (int t = 0; t < CL; t++) {
    const size_t m = m0 + t;
    const float dl = delta[m * DI + d];
    const float uu = u[m * DI + d];
    const float du = dl * uu;
    const float4* bp = reinterpret_cast<const float4*>(&Bb[m * DS]);
    const float4 B0 = bp[0], B1 = bp[1], B2 = bp[2], B3 = bp[3];
    const float4* cp = reinterpret_cast<const float4*>(&Cb[m * DS]);
    const float4 C0 = cp[0], C1 = cp[1], C2 = cp[2], C3 = cp[3];
    const float Bv[16] = {B0.x, B0.y, B0.z, B0.w, B1.x, B1.y, B1.z, B1.w,
                          B2.x, B2.y, B2.z, B2.w, B3.x, B3.y, B3.z, B3.w};
    const float Cv[16] = {C0.x, C0.y, C0.z, C0.w, C1.x, C1.y, C1.z, C1.w,
                          C2.x, C2.y, C2.z, C2.w, C3.x, C3.y, C3.z, C3.w};
    float y = 0.f;
#pragma unroll
    for (int n = 0; n < 16; n++) {
      const float dA = __expf(dl * An[n]);
      h[n] = dA * h[n] + du * Bv[n];
      y += h[n] * Cv[n];
    }
    const float rs = xz[m * 512 + 256 + d];       // already silu'd
    g[m * DI + d] = (y + uu * Dpd) * rs;          // aliases delta (same-thread RAW only)
  }
}

// ---------------- launch ----------------
extern "C" void kernel_launch(void* const* d_in, const int* in_sizes, int n_in,
                              void* d_out, int out_size, void* d_ws, size_t ws_size,
                              hipStream_t stream) {
  const float* x      = (const float*)d_in[0];
  const float* in_w   = (const float*)d_in[1];   // [2,128,512]
  const float* conv_w = (const float*)d_in[2];   // [2,256,1,4]
  const float* conv_b = (const float*)d_in[3];   // [2,256]
  const float* xw     = (const float*)d_in[4];   // [2,256,40]
  const float* dtw    = (const float*)d_in[5];   // [2,8,256]
  const float* dtb    = (const float*)d_in[6];   // [2,256]
  const float* A_log  = (const float*)d_in[7];   // [2,256,16]
  const float* Dp     = (const float*)d_in[8];   // [2,256]
  const float* ow     = (const float*)d_in[9];   // [2,256,128]
  float* out = (float*)d_out;
  float* ws  = (float*)d_ws;

  float* xz = ws;                          // 16384*512; u-pre half hosts P after conv
  float* u  = ws + 8388608;                // 16384*256
  float* dg = ws + 12582912;               // 16384*256 (delta, then g alias)
  float* Bb = ws + 16777216;               // 16384*16
  float* Cb = ws + 17039360;               // 16384*16
  float* hb = ws + 17301504;               // 16384*128
  float* Hb = ws + 19398656;               // NC*SSZ = 2097152 (NC=8), ends 21495808
  // pre-split weight planes (u32 data in float slots), within proven footprint
  unsigned int* pl_w1 = (unsigned int*)(ws + 21495808);  // 2 layers x 98304 u32
  unsigned int* pl_wb = (unsigned int*)(ws + 21692416);  // 2 x 122880
  unsigned int* pl_ow = (unsigned int*)(ws + 21938176);  // 2 x 49152  (ends 22036480)
  // W_big fp32 scratch in d_out (dead after prep; out fully rewritten by final gemm)
  float* Wbig = out;                       // 2*256*320 = 163840 <= out_size

  // ---- weight preprocessing ----
  prep_planes<<<dim3(4 * 32, 2), 64, 0, stream>>>(in_w, pl_w1, 128, 512);
  build_wbig<<<dim3(DI, 2), 320, 0, stream>>>(xw, dtw, Wbig);
  prep_planes<<<dim3(8 * 20, 2), 64, 0, stream>>>(Wbig, pl_wb, 256, 320);
  prep_planes<<<dim3(8 * 8, 2), 64, 0, stream>>>(ow, pl_ow, 256, 128);

  for (int l = 0; l < 2; l++) {
    const float* Ain = (l == 0) ? x : hb;
    float* dst = (l == 1) ? out : hb;

    // gemm1: [16384,128] @ [128,512] -> xz     (2048 waves)
    gemm_mfma<4, 0><<<512, 256, 0, stream>>>(
        Ain, pl_w1 + (size_t)l * 98304, xz, nullptr, nullptr, nullptr,
        M_ROWS, 512, 128);

    conv_silu_kernel<<<M_ROWS, 256, 0, stream>>>(
        xz, xz, conv_w + (size_t)l * DI * 4, conv_b + (size_t)l * DI, u);

    // DBC: [16384,256] @ [256,320] -> delta/B/C  (1280 waves)
    gemm_mfma<4, 1><<<320, 256, 0, stream>>>(
        u, pl_wb + (size_t)l * 122880, dg, Bb, Cb, dtb + (size_t)l * DI,
        M_ROWS, 320, 256);

    scan_phase1<<<dim3(NC, BT), 256, 0, stream>>>(
        dg, u, Bb, A_log + (size_t)l * DI * DS, xz, Hb);

    scan_phase2<<<SSZ / 256, 256, 0, stream>>>(xz, Hb);

    scan_phase3<<<dim3(NC, BT), 256, 0, stream>>>(
        dg, u, Bb, Cb, xz, A_log + (size_t)l * DI * DS, Dp + (size_t)l * DI,
        Hb, dg);

    // gemm3: [16384,256] @ [256,128] -> dst    (1024 waves, CF=2)
    gemm_mfma<2, 0><<<256, 256, 0, stream>>>(
        dg, pl_ow + (size_t)l * 49152, dst, nullptr, nullptr, nullptr,
        M_ROWS, 128, 256);
  }
}

// Round 9
// 277.289 us; speedup vs baseline: 2.0365x; 1.0870x over previous
//
#include <hip/hip_runtime.h>
#include <math.h>

// Problem dims
#define BT 64       // B*N sequences
#define T 256
#define DM 128      // d_model
#define DI 256      // d_inner
#define DS 16       // d_state
#define DR 8        // dt_rank
#define M_ROWS (BT*T)   // 16384
#define NC 16       // time chunks for parallel scan
#define CL (T/NC)   // chunk length = 16
#define SSZ (BT*DI*DS)  // per-chunk state slab = 262144

typedef __attribute__((ext_vector_type(8))) short short8v;   // 8 bf16
typedef __attribute__((ext_vector_type(4))) float f32x4;     // MFMA acc
typedef __attribute__((ext_vector_type(4))) unsigned int uint4v;
union U8 { unsigned int u[4]; uint4v v; short8v s; };

__device__ __forceinline__ float fast_silu(float x) {
  return x * __builtin_amdgcn_rcpf(1.0f + __expf(-x));
}
__device__ __forceinline__ float softplus_f(float x) {
  return fmaxf(x, 0.0f) + __logf(1.0f + __expf(-fabsf(x)));
}

// exact 3-way bf16 split of 8 fp32 (truncation; subtractions exact)
__device__ __forceinline__ void split3(const float* x, short8v& o1, short8v& o2, short8v& o3) {
  unsigned int h1[8], h2[8], h3[8];
#pragma unroll
  for (int e = 0; e < 8; e++) {
    const float xe = x[e];
    const unsigned int a = __float_as_uint(xe) & 0xFFFF0000u;
    const float r1 = xe - __uint_as_float(a);
    const unsigned int b = __float_as_uint(r1) & 0xFFFF0000u;
    const float r2 = r1 - __uint_as_float(b);
    const unsigned int c = __float_as_uint(r2) & 0xFFFF0000u;
    h1[e] = a; h2[e] = b; h3[e] = c;
  }
  U8 u1, u2, u3;
#pragma unroll
  for (int q = 0; q < 4; q++) {
    u1.u[q] = (h1[2 * q] >> 16) | (h1[2 * q + 1] & 0xFFFF0000u);
    u2.u[q] = (h2[2 * q] >> 16) | (h2[2 * q + 1] & 0xFFFF0000u);
    u3.u[q] = (h3[2 * q] >> 16) | (h3[2 * q + 1] & 0xFFFF0000u);
  }
  o1 = u1.s; o2 = u2.s; o3 = u3.s;
}

// ---------------- unified weight prep: split all 3 weight mats into plane layout ----------
// chunk (p, ks, cf): lane l elem e = W[ks*32+(l>>4)*8+e][cf*16+(l&15)]
// u32 idx = (((p*Kt+ks)*NF+cf)*64 + l)*4. W_big (for wb) computed inline from xw/dtw.
__global__ __launch_bounds__(64) void prep_all(
    const float* __restrict__ in_w, const float* __restrict__ xw,
    const float* __restrict__ dtw, const float* __restrict__ ow,
    unsigned int* __restrict__ pw1, unsigned int* __restrict__ pwb,
    unsigned int* __restrict__ pow_) {
  const int b = blockIdx.x;
  const int l = threadIdx.x;
  const int rA = l & 15, kg = l >> 4;
  float x[8];
  unsigned int* dst;
  size_t base;
  if (b < 256) {            // in_w: [128,512] per layer, Kt=4, NF=32
    const int layer = b >> 7, rem = b & 127;
    const int ks = rem >> 5, cf = rem & 31;
    const int col = cf * 16 + rA, k0 = ks * 32 + kg * 8;
    const float* W = in_w + (size_t)layer * 128 * 512;
#pragma unroll
    for (int e = 0; e < 8; e++) x[e] = W[(size_t)(k0 + e) * 512 + col];
    dst = pw1 + (size_t)layer * 98304;
    base = (((size_t)ks * 32 + cf) * 64 + l) * 4;
    short8v p1, p2, p3; split3(x, p1, p2, p3);
    U8 t;
    t.s = p1; *reinterpret_cast<uint4v*>(dst + base) = t.v;
    t.s = p2; *reinterpret_cast<uint4v*>(dst + 32768 + base) = t.v;
    t.s = p3; *reinterpret_cast<uint4v*>(dst + 65536 + base) = t.v;
  } else if (b < 576) {     // W_big: [256,320] per layer (inline), Kt=8, NF=20
    const int bb = b - 256;
    const int layer = bb / 160, rem = bb % 160;
    const int ks = rem / 20, cf = rem % 20;
    const int col = cf * 16 + rA, k0 = ks * 32 + kg * 8;
    const float* xwl = xw + (size_t)layer * DI * 40;
    const float* dtwl = dtw + (size_t)layer * DR * DI;
#pragma unroll
    for (int e = 0; e < 8; e++) {
      const int k = k0 + e;
      float v = 0.f;
      if (col < 256) {
#pragma unroll
        for (int r = 0; r < DR; r++) v += xwl[k * 40 + r] * dtwl[r * DI + col];
      } else if (col < 288) {
        v = xwl[k * 40 + 8 + (col - 256)];
      }
      x[e] = v;
    }
    dst = pwb + (size_t)layer * 122880;
    base = (((size_t)ks * 20 + cf) * 64 + l) * 4;
    short8v p1, p2, p3; split3(x, p1, p2, p3);
    U8 t;
    t.s = p1; *reinterpret_cast<uint4v*>(dst + base) = t.v;
    t.s = p2; *reinterpret_cast<uint4v*>(dst + 40960 + base) = t.v;
    t.s = p3; *reinterpret_cast<uint4v*>(dst + 81920 + base) = t.v;
  } else {                  // ow: [256,128] per layer, Kt=8, NF=8
    const int bb = b - 576;
    const int layer = bb >> 6, rem = bb & 63;
    const int ks = rem >> 3, cf = rem & 7;
    const int col = cf * 16 + rA, k0 = ks * 32 + kg * 8;
    const float* W = ow + (size_t)layer * 256 * 128;
#pragma unroll
    for (int e = 0; e < 8; e++) x[e] = W[(size_t)(k0 + e) * 128 + col];
    dst = pow_ + (size_t)layer * 49152;
    base = (((size_t)ks * 8 + cf) * 64 + l) * 4;
    short8v p1, p2, p3; split3(x, p1, p2, p3);
    U8 t;
    t.s = p1; *reinterpret_cast<uint4v*>(dst + base) = t.v;
    t.s = p2; *reinterpret_cast<uint4v*>(dst + 16384 + base) = t.v;
    t.s = p3; *reinterpret_cast<uint4v*>(dst + 32768 + base) = t.v;
  }
}

// ---------------- MFMA split-bf16 GEMM: wave-per-(16*FR)x(16*CF) tile, no LDS ------------
// 6-term split accumulation into fp32 acc. B from pre-split planes (frag-direct b128),
// A fp32 from global, split in-reg. C map (m89): row=(l>>4)*4+reg, col=l&15.
// EPI=0: plain store (stride Nn). EPI=1: col<256 softplus(+dtb)->C stride DI;
//   col 256-271 -> Bb; 272-287 -> Cb; >=288 discard (W zero-padded).
template <int FR, int CF, int EPI>
__global__ __launch_bounds__(256, 2) void gemm_mfma(
    const float* __restrict__ A, const unsigned int* __restrict__ Bp,
    float* __restrict__ C, float* __restrict__ Bb, float* __restrict__ Cb,
    const float* __restrict__ dtb, int M, int Nn, int K) {
  const int NWC = Nn / (16 * CF);
  const int wid = blockIdx.x * 4 + (threadIdx.x >> 6);
  const int l = threadIdx.x & 63;
  const int mw = wid / NWC, nw = wid % NWC;
  const int wr0 = mw * (16 * FR), wc0 = nw * (16 * CF);
  const int rA = l & 15, kg = l >> 4;
  const int NF = Nn / 16, Kt = K >> 5;

  f32x4 acc[FR][CF];
#pragma unroll
  for (int fr = 0; fr < FR; fr++)
#pragma unroll
    for (int j = 0; j < CF; j++) acc[fr][j] = (f32x4){0.f, 0.f, 0.f, 0.f};

  for (int ks = 0; ks < Kt; ks++) {
    short8v bf[3][CF];
#pragma unroll
    for (int p = 0; p < 3; p++)
#pragma unroll
      for (int j = 0; j < CF; j++) {
        U8 t;
        t.v = *reinterpret_cast<const uint4v*>(
            Bp + ((((size_t)p * Kt + ks) * NF + (wc0 >> 4) + j) * 64 + l) * 4);
        bf[p][j] = t.s;
      }
    short8v a1[FR], a2[FR], a3[FR];
#pragma unroll
    for (int fr = 0; fr < FR; fr++) {
      const float* ap = A + (size_t)(wr0 + fr * 16 + rA) * K + ks * 32 + kg * 8;
      float x[8];
      *reinterpret_cast<float4*>(x) = *reinterpret_cast<const float4*>(ap);
      *reinterpret_cast<float4*>(x + 4) = *reinterpret_cast<const float4*>(ap + 4);
      split3(x, a1[fr], a2[fr], a3[fr]);
    }
#pragma unroll
    for (int fr = 0; fr < FR; fr++)
#pragma unroll
      for (int j = 0; j < CF; j++) {
        f32x4 c = acc[fr][j];
        c = __builtin_amdgcn_mfma_f32_16x16x32_bf16(a1[fr], bf[0][j], c, 0, 0, 0);
        c = __builtin_amdgcn_mfma_f32_16x16x32_bf16(a1[fr], bf[1][j], c, 0, 0, 0);
        c = __builtin_amdgcn_mfma_f32_16x16x32_bf16(a2[fr], bf[0][j], c, 0, 0, 0);
        c = __builtin_amdgcn_mfma_f32_16x16x32_bf16(a1[fr], bf[2][j], c, 0, 0, 0);
        c = __builtin_amdgcn_mfma_f32_16x16x32_bf16(a3[fr], bf[0][j], c, 0, 0, 0);
        c = __builtin_amdgcn_mfma_f32_16x16x32_bf16(a2[fr], bf[1][j], c, 0, 0, 0);
        acc[fr][j] = c;
      }
  }

  const int cr = (l >> 4) * 4;
  const int cc = l & 15;
  if (EPI == 0) {
#pragma unroll
    for (int fr = 0; fr < FR; fr++)
#pragma unroll
      for (int j = 0; j < CF; j++) {
        const int col = wc0 + j * 16 + cc;
#pragma unroll
        for (int r = 0; r < 4; r++)
          C[(size_t)(wr0 + fr * 16 + cr + r) * Nn + col] = acc[fr][j][r];
      }
  } else {
#pragma unroll
    for (int fr = 0; fr < FR; fr++)
#pragma unroll
      for (int j = 0; j < CF; j++) {
        const int col = wc0 + j * 16 + cc;
        if (col < 256) {
          const float bias = dtb[col];
#pragma unroll
          for (int r = 0; r < 4; r++)
            C[(size_t)(wr0 + fr * 16 + cr + r) * DI + col] =
                softplus_f(acc[fr][j][r] + bias);
        } else if (col < 272) {
#pragma unroll
          for (int r = 0; r < 4; r++)
            Bb[(size_t)(wr0 + fr * 16 + cr + r) * DS + (col - 256)] = acc[fr][j][r];
        } else if (col < 288) {
#pragma unroll
          for (int r = 0; r < 4; r++)
            Cb[(size_t)(wr0 + fr * 16 + cr + r) * DS + (col - 272)] = acc[fr][j][r];
        }
      }
  }
}

// ---------------- depthwise causal conv (4-tap) + bias + silu; silu(res) in place --------
// one block = 8 consecutive time rows, register sliding window
__global__ __launch_bounds__(256) void conv_silu_kernel(
    const float* __restrict__ xzr, float* __restrict__ xzw,
    const float* __restrict__ cw, const float* __restrict__ cb,
    float* __restrict__ u) {
  const int d = threadIdx.x;
  const int m0 = blockIdx.x * 8;
  const int t0 = m0 & (T - 1);
  const float4 cv = *reinterpret_cast<const float4*>(&cw[d * 4]);
  const float bias = cb[d];
  float w0 = 0.f, w1 = 0.f, w2 = 0.f;
  if (t0 != 0) {   // t0 is a multiple of 8, so t0>=8>3: history fully in-bounds
    w0 = xzr[(size_t)(m0 - 3) * 512 + d];
    w1 = xzr[(size_t)(m0 - 2) * 512 + d];
    w2 = xzr[(size_t)(m0 - 1) * 512 + d];
  }
#pragma unroll
  for (int i = 0; i < 8; i++) {
    const size_t m = m0 + i;
    const float cur = xzr[m * 512 + d];
    const float a = bias + cv.x * w0 + cv.y * w1 + cv.z * w2 + cv.w * cur;
    u[m * DI + d] = fast_silu(a);
    const float r = xzr[m * 512 + 256 + d];
    xzw[m * 512 + 256 + d] = fast_silu(r);
    w0 = w1; w1 = w2; w2 = cur;
  }
}

// ---------------- chunked parallel scan (all 16 n-states per thread) ----------------
__global__ __launch_bounds__(256) void scan_phase1(
    const float* __restrict__ delta, const float* __restrict__ u,
    const float* __restrict__ Bb, const float* __restrict__ A_log,
    float* __restrict__ Pb, float* __restrict__ H) {
  const int c  = blockIdx.x;
  const int bt = blockIdx.y;
  const int d  = threadIdx.x;

  float An[16];
  const float4* al = reinterpret_cast<const float4*>(&A_log[d * DS]);
#pragma unroll
  for (int q = 0; q < 4; q++) {
    float4 a = al[q];
    An[q * 4 + 0] = -__expf(a.x);
    An[q * 4 + 1] = -__expf(a.y);
    An[q * 4 + 2] = -__expf(a.z);
    An[q * 4 + 3] = -__expf(a.w);
  }

  float h[16];
#pragma unroll
  for (int n = 0; n < 16; n++) h[n] = 0.f;
  float Sdl = 0.f;

  const size_t m0 = (size_t)bt * T + c * CL;
  for (int t = 0; t < CL; t++) {
    const size_t m = m0 + t;
    const float dl = delta[m * DI + d];
    const float uu = u[m * DI + d];
    const float du = dl * uu;
    Sdl += dl;
    const float4* bp = reinterpret_cast<const float4*>(&Bb[m * DS]);
    const float4 B0 = bp[0], B1 = bp[1], B2 = bp[2], B3 = bp[3];
    const float Bv[16] = {B0.x, B0.y, B0.z, B0.w, B1.x, B1.y, B1.z, B1.w,
                          B2.x, B2.y, B2.z, B2.w, B3.x, B3.y, B3.z, B3.w};
#pragma unroll
    for (int n = 0; n < 16; n++) {
      const float dA = __expf(dl * An[n]);
      h[n] = dA * h[n] + du * Bv[n];
    }
  }

  const size_t idx = ((size_t)c * BT + bt) * 4096 + (size_t)d * 16;
#pragma unroll
  for (int q = 0; q < 4; q++) {
    float4 hv = {h[q * 4 + 0], h[q * 4 + 1], h[q * 4 + 2], h[q * 4 + 3]};
    *reinterpret_cast<float4*>(&H[idx + q * 4]) = hv;
  }
#pragma unroll
  for (int q = 0; q < 4; q++) {
    float4 pv = {__expf(An[q * 4 + 0] * Sdl), __expf(An[q * 4 + 1] * Sdl),
                 __expf(An[q * 4 + 2] * Sdl), __expf(An[q * 4 + 3] * Sdl)};
    *reinterpret_cast<float4*>(&Pb[idx + q * 4]) = pv;
  }
}

__global__ __launch_bounds__(256) void scan_phase2(
    const float* __restrict__ Pb, float* __restrict__ H) {
  const size_t i = (size_t)blockIdx.x * 256 + threadIdx.x;   // 0..SSZ-1
  float hin = 0.f;
#pragma unroll
  for (int c = 0; c < NC; c++) {
    const size_t idx = (size_t)c * SSZ + i;
    const float Pv = Pb[idx];
    const float Hv = H[idx];
    H[idx] = hin;
    hin = Pv * hin + Hv;
  }
}

__global__ __launch_bounds__(256) void scan_phase3(
    const float* __restrict__ delta, const float* __restrict__ u,
    const float* __restrict__ Bb, const float* __restrict__ Cb,
    const float* __restrict__ xz,            // res half pre-silu'd by conv kernel
    const float* __restrict__ A_log, const float* __restrict__ Dp,
    const float* __restrict__ H, float* __restrict__ g) {
  const int c  = blockIdx.x;
  const int bt = blockIdx.y;
  const int d  = threadIdx.x;

  float An[16];
  const float4* al = reinterpret_cast<const float4*>(&A_log[d * DS]);
#pragma unroll
  for (int q = 0; q < 4; q++) {
    float4 a = al[q];
    An[q * 4 + 0] = -__expf(a.x);
    An[q * 4 + 1] = -__expf(a.y);
    An[q * 4 + 2] = -__expf(a.z);
    An[q * 4 + 3] = -__expf(a.w);
  }
  const float Dpd = Dp[d];

  float h[16];
  const size_t idx = ((size_t)c * BT + bt) * 4096 + (size_t)d * 16;
#pragma unroll
  for (int q = 0; q < 4; q++) {
    float4 hv = *reinterpret_cast<const float4*>(&H[idx + q * 4]);
    h[q * 4 + 0] = hv.x; h[q * 4 + 1] = hv.y; h[q * 4 + 2] = hv.z; h[q * 4 + 3] = hv.w;
  }

  const size_t m0 = (size_t)bt * T + c * CL;
  for (int t = 0; t < CL; t++) {
    const size_t m = m0 + t;
    const float dl = delta[m * DI + d];
    const float uu = u[m * DI + d];
    const float du = dl * uu;
    const float4* bp = reinterpret_cast<const float4*>(&Bb[m * DS]);
    const float4 B0 = bp[0], B1 = bp[1], B2 = bp[2], B3 = bp[3];
    const float4* cp = reinterpret_cast<const float4*>(&Cb[m * DS]);
    const float4 C0 = cp[0], C1 = cp[1], C2 = cp[2], C3 = cp[3];
    const float Bv[16] = {B0.x, B0.y, B0.z, B0.w, B1.x, B1.y, B1.z, B1.w,
                          B2.x, B2.y, B2.z, B2.w, B3.x, B3.y, B3.z, B3.w};
    const float Cv[16] = {C0.x, C0.y, C0.z, C0.w, C1.x, C1.y, C1.z, C1.w,
                          C2.x, C2.y, C2.z, C2.w, C3.x, C3.y, C3.z, C3.w};
    float y = 0.f;
#pragma unroll
    for (int n = 0; n < 16; n++) {
      const float dA = __expf(dl * An[n]);
      h[n] = dA * h[n] + du * Bv[n];
      y += h[n] * Cv[n];
    }
    const float rs = xz[m * 512 + 256 + d];       // already silu'd
    g[m * DI + d] = (y + uu * Dpd) * rs;          // aliases delta (same-thread RAW only)
  }
}

// ---------------- launch ----------------
extern "C" void kernel_launch(void* const* d_in, const int* in_sizes, int n_in,
                              void* d_out, int out_size, void* d_ws, size_t ws_size,
                              hipStream_t stream) {
  const float* x      = (const float*)d_in[0];
  const float* in_w   = (const float*)d_in[1];   // [2,128,512]
  const float* conv_w = (const float*)d_in[2];   // [2,256,1,4]
  const float* conv_b = (const float*)d_in[3];   // [2,256]
  const float* xw     = (const float*)d_in[4];   // [2,256,40]
  const float* dtw    = (const float*)d_in[5];   // [2,8,256]
  const float* dtb    = (const float*)d_in[6];   // [2,256]
  const float* A_log  = (const float*)d_in[7];   // [2,256,16]
  const float* Dp     = (const float*)d_in[8];   // [2,256]
  const float* ow     = (const float*)d_in[9];   // [2,256,128]
  float* out = (float*)d_out;
  float* ws  = (float*)d_ws;

  float* xz = ws;                          // 16384*512
  float* u  = ws + 8388608;                // 16384*256
  float* dg = ws + 12582912;               // 16384*256 (delta, then g alias)
  float* Bb = ws + 16777216;               // 16384*16
  float* Cb = ws + 17039360;               // 16384*16
  float* hb = ws + 17301504;               // 16384*128  ends 19398656
  float* Hb = ws + 19398656;               // NC*SSZ = 4194304, ends 23592960
  float* Pb = ws + 23592960;               // NC*SSZ = 4194304, ends 27787264
  unsigned int* pl_w1 = (unsigned int*)(ws + 27787264);  // 2 x 98304 u32
  unsigned int* pl_wb = (unsigned int*)(ws + 27983872);  // 2 x 122880
  unsigned int* pl_ow = (unsigned int*)(ws + 28229632);  // 2 x 49152, ends 28327936 (113.3MB)

  prep_all<<<704, 64, 0, stream>>>(in_w, xw, dtw, ow, pl_w1, pl_wb, pl_ow);

  for (int l = 0; l < 2; l++) {
    const float* Ain = (l == 0) ? x : hb;
    float* dst = (l == 1) ? out : hb;

    // gemm1: [16384,128]@[128,512] -> xz. FR=4,CF=2: 4096 waves, 1024 blocks
    gemm_mfma<4, 2, 0><<<1024, 256, 0, stream>>>(
        Ain, pl_w1 + (size_t)l * 98304, xz, nullptr, nullptr, nullptr,
        M_ROWS, 512, 128);

    conv_silu_kernel<<<M_ROWS / 8, 256, 0, stream>>>(
        xz, xz, conv_w + (size_t)l * DI * 4, conv_b + (size_t)l * DI, u);

    // DBC: [16384,256]@[256,320] -> delta/B/C. FR=4,CF=2: 2560 waves, 640 blocks
    gemm_mfma<4, 2, 1><<<640, 256, 0, stream>>>(
        u, pl_wb + (size_t)l * 122880, dg, Bb, Cb, dtb + (size_t)l * DI,
        M_ROWS, 320, 256);

    scan_phase1<<<dim3(NC, BT), 256, 0, stream>>>(
        dg, u, Bb, A_log + (size_t)l * DI * DS, Pb, Hb);

    scan_phase2<<<SSZ / 256, 256, 0, stream>>>(Pb, Hb);

    scan_phase3<<<dim3(NC, BT), 256, 0, stream>>>(
        dg, u, Bb, Cb, xz, A_log + (size_t)l * DI * DS, Dp + (size_t)l * DI,
        Hb, dg);

    // gemm3: [16384,256]@[256,128] -> dst. FR=2,CF=2: 2048 waves, 512 blocks
    gemm_mfma<2, 2, 0><<<512, 256, 0, stream>>>(
        dg, pl_ow + (size_t)l * 49152, dst, nullptr, nullptr, nullptr,
        M_ROWS, 128, 256);
  }
}